// Round 1
// baseline (103.801 us; speedup 1.0000x reference)
//
#include <hip/hip_runtime.h>

// GhostVLAD: N=32, C=512, H=16, W=32 -> L=512, KG=10 (8 kept + 2 ghost)
#define N_   32
#define C_   512
#define L_   512
#define KG_  10
#define K_   8
#define LCH  8     // number of l-chunks
#define LT   64    // l per chunk
#define EPSF 1e-12f

// ---------------------------------------------------------------------------
// Kernel 1: logits = conv_w @ x + b, softmax over k, store a[k<8], asum partials
// grid (N, LCH), block 512. Wave w handles c-range [w*64, w*64+64), lanes <-> l.
// ---------------------------------------------------------------------------
__global__ __launch_bounds__(512) void k_softmax(
    const float* __restrict__ x, const float* __restrict__ cw,
    const float* __restrict__ cb, float* __restrict__ a_out,
    float* __restrict__ asum_part)
{
    const int n   = blockIdx.x;
    const int ch  = blockIdx.y;
    const int tid = threadIdx.x;
    const int l   = tid & 63;
    const int cg  = tid >> 6;            // 0..7 (wave id, uniform per wave)
    const int lg  = ch * LT + l;

    const float* xn = x + (size_t)n * C_ * L_;

    float acc[KG_];
#pragma unroll
    for (int k = 0; k < KG_; ++k) acc[k] = 0.f;

    const int c0 = cg * 64;
#pragma unroll 4
    for (int ci = 0; ci < 64; ++ci) {
        const int c = c0 + ci;
        const float xv = xn[(size_t)c * L_ + lg];   // coalesced: lanes -> l
#pragma unroll
        for (int k = 0; k < KG_; ++k)
            acc[k] += cw[k * C_ + c] * xv;          // uniform addr -> scalar load
    }

    __shared__ float red[8][LT][KG_];               // 20 KB
#pragma unroll
    for (int k = 0; k < KG_; ++k) red[cg][l][k] = acc[k];
    __syncthreads();

    __shared__ float lgs[LT][KG_];                  // 2.5 KB
    for (int idx = tid; idx < LT * KG_; idx += 512) {
        const int li = idx / KG_, k = idx % KG_;
        float s = 0.f;
#pragma unroll
        for (int g = 0; g < 8; ++g) s += red[g][li][k];
        lgs[li][k] = s;
    }
    __syncthreads();

    if (tid < LT) {   // wave 0 exactly; lane <-> l
        float v[KG_];
        float m = -1e30f;
#pragma unroll
        for (int k = 0; k < KG_; ++k) {
            v[k] = lgs[tid][k] + cb[k];
            m = fmaxf(m, v[k]);
        }
        float s = 0.f;
#pragma unroll
        for (int k = 0; k < KG_; ++k) { v[k] = __expf(v[k] - m); s += v[k]; }
        const float inv = 1.f / s;
        const int lgl = ch * LT + tid;
#pragma unroll
        for (int k = 0; k < K_; ++k) {
            const float av = v[k] * inv;
            a_out[((size_t)n * K_ + k) * L_ + lgl] = av;  // coalesced: lanes -> l
            float t = av;                                  // wave-reduce over 64 l
#pragma unroll
            for (int off = 32; off > 0; off >>= 1) t += __shfl_down(t, off);
            if (tid == 0)
                asum_part[((size_t)n * LCH + ch) * K_ + k] = t;
        }
    }
}

// ---------------------------------------------------------------------------
// Kernel 2: assign_x[n,k,c] += sum_{l in chunk} a[n,k,l] * x[n,c,l]
// grid (N, LCH), block 512. LDS-transposed x tile [c][65] (conflict-free),
// thread <-> c, a-loads are wave-uniform (scalar), atomicAdd accumulation.
// ---------------------------------------------------------------------------
__global__ __launch_bounds__(512) void k_assign(
    const float* __restrict__ x, const float* __restrict__ a,
    float* __restrict__ assign_x)
{
    const int n   = blockIdx.x;
    const int ch  = blockIdx.y;
    const int tid = threadIdx.x;

    __shared__ float xs[C_ * 65];   // 133,120 B of 160 KB

    const float* xbase = x + (size_t)n * C_ * L_ + ch * LT;
    // stage: 512 rows x 16 float4 each; coalesced 16B loads, 2-lane/bank LDS stores
    for (int it = tid; it < C_ * 16; it += 512) {
        const int c = it >> 4, q = it & 15;
        const float4 v = *reinterpret_cast<const float4*>(xbase + (size_t)c * L_ + q * 4);
        const int b = c * 65 + q * 4;
        xs[b]     = v.x;
        xs[b + 1] = v.y;
        xs[b + 2] = v.z;
        xs[b + 3] = v.w;
    }
    __syncthreads();

    const int c = tid;   // 512 threads <-> 512 c
    const float* arow = a + (size_t)n * K_ * L_ + ch * LT;

    float acc[K_];
#pragma unroll
    for (int k = 0; k < K_; ++k) acc[k] = 0.f;

#pragma unroll 2
    for (int li = 0; li < LT; ++li) {
        const float xv = xs[c * 65 + li];           // bank = (c+li)%32: conflict-free
#pragma unroll
        for (int k = 0; k < K_; ++k)
            acc[k] += arow[k * L_ + li] * xv;       // uniform addr -> scalar load
    }

#pragma unroll
    for (int k = 0; k < K_; ++k)
        atomicAdd(&assign_x[((size_t)n * K_ + k) * C_ + c], acc[k]);  // coalesced
}

// ---------------------------------------------------------------------------
// Kernel 3: residual vs centers, per-k l2norm, global l2norm, write out.
// grid N, block 256 (thread handles c = tid, tid+256).
// ---------------------------------------------------------------------------
__global__ __launch_bounds__(256) void k_final(
    const float* __restrict__ assign_x, const float* __restrict__ asum_part,
    const float* __restrict__ centers, float* __restrict__ out)
{
    const int n    = blockIdx.x;
    const int tid  = threadIdx.x;
    const int lane = tid & 63;
    const int wv   = tid >> 6;

    __shared__ float s_asum[K_];
    __shared__ float s_inv[K_];
    __shared__ float s_q[K_];
    __shared__ float s_ginv;
    __shared__ float wred[4][K_];

    if (tid < K_) {
        float s = 0.f;
#pragma unroll
        for (int c2 = 0; c2 < LCH; ++c2)
            s += asum_part[((size_t)n * LCH + c2) * K_ + tid];
        s_asum[tid] = s;
    }
    __syncthreads();

    float r[K_][2];
    float ssq[K_];
#pragma unroll
    for (int k = 0; k < K_; ++k) ssq[k] = 0.f;

#pragma unroll
    for (int j = 0; j < 2; ++j) {
        const int c = tid + j * 256;
#pragma unroll
        for (int k = 0; k < K_; ++k) {
            const float v = assign_x[((size_t)n * K_ + k) * C_ + c]
                          - s_asum[k] * centers[k * C_ + c];
            r[k][j] = v;
            ssq[k] += v * v;
        }
    }

#pragma unroll
    for (int k = 0; k < K_; ++k) {
        float t = ssq[k];
#pragma unroll
        for (int off = 32; off > 0; off >>= 1) t += __shfl_down(t, off);
        if (lane == 0) wred[wv][k] = t;
    }
    __syncthreads();

    if (tid < K_) {
        const float t = wred[0][tid] + wred[1][tid] + wred[2][tid] + wred[3][tid];
        const float inv = 1.f / fmaxf(sqrtf(t), EPSF);
        s_inv[tid] = inv;
        s_q[tid]   = t * inv * inv;   // contribution to global sumsq
    }
    __syncthreads();

    if (tid == 0) {
        float g = 0.f;
#pragma unroll
        for (int k = 0; k < K_; ++k) g += s_q[k];
        s_ginv = 1.f / fmaxf(sqrtf(g), EPSF);
    }
    __syncthreads();

    const float ginv = s_ginv;
#pragma unroll
    for (int j = 0; j < 2; ++j) {
        const int c = tid + j * 256;
#pragma unroll
        for (int k = 0; k < K_; ++k)
            out[(size_t)n * (K_ * C_) + k * C_ + c] = r[k][j] * s_inv[k] * ginv;
    }
}

// ---------------------------------------------------------------------------
extern "C" void kernel_launch(void* const* d_in, const int* in_sizes, int n_in,
                              void* d_out, int out_size, void* d_ws, size_t ws_size,
                              hipStream_t stream)
{
    const float* x       = (const float*)d_in[0];  // (32,512,16,32)
    const float* conv_w  = (const float*)d_in[1];  // (10,512)
    const float* conv_b  = (const float*)d_in[2];  // (10,)
    const float* centers = (const float*)d_in[3];  // (10,512)
    float* out = (float*)d_out;                    // (32, 4096)

    // workspace layout (floats): a[N*8*L] | asum_part[N*8*8] | assign_x[N*8*C]
    float* a         = (float*)d_ws;               // 131072
    float* asum_part = a + (size_t)N_ * K_ * L_;   // 2048
    float* assign_x  = asum_part + (size_t)N_ * LCH * K_; // 131072

    hipMemsetAsync(assign_x, 0, sizeof(float) * N_ * K_ * C_, stream);

    dim3 grid(N_, LCH);
    hipLaunchKernelGGL(k_softmax, grid, dim3(512), 0, stream,
                       x, conv_w, conv_b, a, asum_part);
    hipLaunchKernelGGL(k_assign, grid, dim3(512), 0, stream,
                       x, a, assign_x);
    hipLaunchKernelGGL(k_final, dim3(N_), dim3(256), 0, stream,
                       assign_x, asum_part, centers, out);
}

// Round 2
// 95.539 us; speedup vs baseline: 1.0865x; 1.0865x over previous
//
#include <hip/hip_runtime.h>

// GhostVLAD: N=32, C=512, L=512, KG=10 (8 kept + 2 ghost), fp32
#define N_   32
#define C_   512
#define L_   512
#define KG_  10
#define K_   8
#define LCH  8     // l-chunks per image
#define LT   64    // l per chunk
#define XP   65    // xs row stride (pad: conflict-free for lanes->l AND lanes->c)
#define RP   11    // red row stride (gcd(11,32)=1 -> conflict-free)
#define EPSF 1e-12f

// ---------------------------------------------------------------------------
// Fused kernel: stage x tile -> logits -> softmax -> assign partials.
// grid (N, LCH), block 512, 1 block/CU (LDS-bound), 157.7 KB LDS.
// ---------------------------------------------------------------------------
__global__ __launch_bounds__(512, 2) void k_main(
    const float* __restrict__ x, const float* __restrict__ cw,
    const float* __restrict__ cb, float* __restrict__ part,
    float* __restrict__ asum_part)
{
    __shared__ float xs[C_ * XP];       // 133,120 B
    __shared__ float red[8][LT][RP];    //  22,528 B
    __shared__ float a_s[LT][K_];       //   2,048 B

    const int n   = blockIdx.x;
    const int ch  = blockIdx.y;
    const int tid = threadIdx.x;

    // ---- stage x tile [512 c][64 l] into LDS (coalesced float4 reads) ----
    const float* xbase = x + (size_t)n * C_ * L_ + ch * LT;
#pragma unroll
    for (int j = 0; j < 16; ++j) {
        const int it = tid + j * 512;
        const int c = it >> 4, q = it & 15;
        const float4 v = *reinterpret_cast<const float4*>(xbase + (size_t)c * L_ + q * 4);
        const int b = c * XP + q * 4;
        xs[b]     = v.x;
        xs[b + 1] = v.y;
        xs[b + 2] = v.z;
        xs[b + 3] = v.w;
    }
    __syncthreads();

    // ---- phase A: logits[k][l] partials; wave cg owns c-range [cg*64, +64) ----
    const int l  = tid & 63;
    const int cg = tid >> 6;
    const int c0 = __builtin_amdgcn_readfirstlane(cg) << 6;  // force wave-uniform

    float acc[KG_];
#pragma unroll
    for (int k = 0; k < KG_; ++k) acc[k] = 0.f;

#pragma unroll
    for (int h = 0; h < 4; ++h) {
        const int cbase = c0 + h * 16;
        float xr[16];
#pragma unroll
        for (int ci = 0; ci < 16; ++ci)
            xr[ci] = xs[(cbase + ci) * XP + l];     // lanes->l stride 1: conflict-free
#pragma unroll
        for (int k = 0; k < KG_; ++k) {
            const float* w = cw + k * C_ + cbase;   // uniform addr -> s_load
#pragma unroll
            for (int ci = 0; ci < 16; ++ci)
                acc[k] = fmaf(w[ci], xr[ci], acc[k]);
        }
    }

#pragma unroll
    for (int k = 0; k < KG_; ++k) red[cg][l][k] = acc[k];
    __syncthreads();

    // reduce over the 8 c-groups into red[0]
    for (int idx = tid; idx < LT * KG_; idx += 512) {
        const int li = idx / KG_, k = idx - li * KG_;
        float s = red[0][li][k];
#pragma unroll
        for (int g = 1; g < 8; ++g) s += red[g][li][k];
        red[0][li][k] = s;
    }
    __syncthreads();

    // ---- softmax over 10 k (wave 0, lane <-> l); a for k<8 into LDS ----
    if (tid < LT) {
        float v[KG_];
        float m = -1e30f;
#pragma unroll
        for (int k = 0; k < KG_; ++k) {
            v[k] = red[0][tid][k] + cb[k];
            m = fmaxf(m, v[k]);
        }
        float s = 0.f;
#pragma unroll
        for (int k = 0; k < KG_; ++k) { v[k] = __expf(v[k] - m); s += v[k]; }
        const float inv = 1.f / s;
#pragma unroll
        for (int k = 0; k < K_; ++k) {
            const float av = v[k] * inv;
            a_s[tid][k] = av;
            float t = av;                            // assign_sum over the 64 l
#pragma unroll
            for (int off = 32; off > 0; off >>= 1) t += __shfl_down(t, off);
            if (tid == 0)
                asum_part[((size_t)n * LCH + ch) * K_ + k] = t;
        }
    }
    __syncthreads();

    // ---- phase B: assign partial[k][c] = sum_l a[k][l] * x[c][l]; thread <-> c ----
    const int c = tid;
    float bacc[K_];
#pragma unroll
    for (int k = 0; k < K_; ++k) bacc[k] = 0.f;

#pragma unroll 4
    for (int li = 0; li < LT; ++li) {
        const float xv = xs[c * XP + li];            // lanes->c: (c+li)%32, conflict-free
        const float4 a0 = *reinterpret_cast<const float4*>(&a_s[li][0]);  // broadcast
        const float4 a1 = *reinterpret_cast<const float4*>(&a_s[li][4]);  // broadcast
        bacc[0] = fmaf(a0.x, xv, bacc[0]);
        bacc[1] = fmaf(a0.y, xv, bacc[1]);
        bacc[2] = fmaf(a0.z, xv, bacc[2]);
        bacc[3] = fmaf(a0.w, xv, bacc[3]);
        bacc[4] = fmaf(a1.x, xv, bacc[4]);
        bacc[5] = fmaf(a1.y, xv, bacc[5]);
        bacc[6] = fmaf(a1.z, xv, bacc[6]);
        bacc[7] = fmaf(a1.w, xv, bacc[7]);
    }

    float* pp = part + (((size_t)n * LCH + ch) * K_) * C_ + c;
#pragma unroll
    for (int k = 0; k < K_; ++k)
        pp[(size_t)k * C_] = bacc[k];                // coalesced stores, no atomics
}

// ---------------------------------------------------------------------------
// k_final: reduce chunk partials, residual vs centers, per-k L2, global L2.
// grid N, block 256 (thread handles c = tid, tid+256).
// ---------------------------------------------------------------------------
__global__ __launch_bounds__(256) void k_final(
    const float* __restrict__ part, const float* __restrict__ asum_part,
    const float* __restrict__ centers, float* __restrict__ out)
{
    const int n    = blockIdx.x;
    const int tid  = threadIdx.x;
    const int lane = tid & 63;
    const int wv   = tid >> 6;

    __shared__ float s_asum[K_];
    __shared__ float s_inv[K_];
    __shared__ float s_q[K_];
    __shared__ float s_ginv;
    __shared__ float wred[4][K_];

    if (tid < K_) {
        float s = 0.f;
#pragma unroll
        for (int c2 = 0; c2 < LCH; ++c2)
            s += asum_part[((size_t)n * LCH + c2) * K_ + tid];
        s_asum[tid] = s;
    }
    __syncthreads();

    float r[K_][2];
    float ssq[K_];
#pragma unroll
    for (int k = 0; k < K_; ++k) ssq[k] = 0.f;

#pragma unroll
    for (int j = 0; j < 2; ++j) {
        const int c = tid + j * 256;
#pragma unroll
        for (int k = 0; k < K_; ++k) {
            float v = 0.f;
#pragma unroll
            for (int c2 = 0; c2 < LCH; ++c2)
                v += part[(((size_t)n * LCH + c2) * K_ + k) * C_ + c];
            v -= s_asum[k] * centers[k * C_ + c];
            r[k][j] = v;
            ssq[k] += v * v;
        }
    }

#pragma unroll
    for (int k = 0; k < K_; ++k) {
        float t = ssq[k];
#pragma unroll
        for (int off = 32; off > 0; off >>= 1) t += __shfl_down(t, off);
        if (lane == 0) wred[wv][k] = t;
    }
    __syncthreads();

    if (tid < K_) {
        const float t = wred[0][tid] + wred[1][tid] + wred[2][tid] + wred[3][tid];
        const float inv = 1.f / fmaxf(sqrtf(t), EPSF);
        s_inv[tid] = inv;
        s_q[tid]   = t * inv * inv;
    }
    __syncthreads();

    if (tid == 0) {
        float g = 0.f;
#pragma unroll
        for (int k = 0; k < K_; ++k) g += s_q[k];
        s_ginv = 1.f / fmaxf(sqrtf(g), EPSF);
    }
    __syncthreads();

    const float ginv = s_ginv;
#pragma unroll
    for (int j = 0; j < 2; ++j) {
        const int c = tid + j * 256;
#pragma unroll
        for (int k = 0; k < K_; ++k)
            out[(size_t)n * (K_ * C_) + k * C_ + c] = r[k][j] * s_inv[k] * ginv;
    }
}

// ---------------------------------------------------------------------------
extern "C" void kernel_launch(void* const* d_in, const int* in_sizes, int n_in,
                              void* d_out, int out_size, void* d_ws, size_t ws_size,
                              hipStream_t stream)
{
    const float* x       = (const float*)d_in[0];  // (32,512,16,32)
    const float* conv_w  = (const float*)d_in[1];  // (10,512)
    const float* conv_b  = (const float*)d_in[2];  // (10,)
    const float* centers = (const float*)d_in[3];  // (10,512)
    float* out = (float*)d_out;                    // (32, 4096)

    // ws layout (floats): part[N*LCH*K*C = 1,048,576] | asum_part[N*LCH*K = 2048]
    float* part      = (float*)d_ws;
    float* asum_part = part + (size_t)N_ * LCH * K_ * C_;

    dim3 grid(N_, LCH);
    hipLaunchKernelGGL(k_main, grid, dim3(512), 0, stream,
                       x, conv_w, conv_b, part, asum_part);
    hipLaunchKernelGGL(k_final, dim3(N_), dim3(256), 0, stream,
                       part, asum_part, centers, out);
}

// Round 3
// 93.401 us; speedup vs baseline: 1.1114x; 1.0229x over previous
//
#include <hip/hip_runtime.h>

// GhostVLAD: N=32, C=512, L=512, KG=10 (8 kept + 2 ghost), fp32
#define N_   32
#define C_   512
#define L_   512
#define KG_  10
#define K_   8
#define LCH  8     // l-chunks per image
#define LT   64    // l per chunk
#define XP   65    // xs row stride (pad: conflict-free for lanes->l AND lanes->c)
#define RP   11    // red row stride (gcd(11,32)=1 -> conflict-free)
#define EPSF 1e-12f

// ---------------------------------------------------------------------------
// Fused kernel: stage x tile -> logits -> softmax -> assign partials.
// grid (N, LCH), block 512, 1 block/CU (LDS-bound), 157.7 KB LDS.
// Staging is split into two c-halves with both halves' global loads issued
// up front: phase A on half0 overlaps the in-flight HBM stream of half1
// (the half1 ds_write waits on its own loads via compiler vmcnt data deps).
// ---------------------------------------------------------------------------
__global__ __launch_bounds__(512, 2) void k_main(
    const float* __restrict__ x, const float* __restrict__ cw,
    const float* __restrict__ cb, float* __restrict__ part,
    float* __restrict__ asum_part)
{
    __shared__ float xs[C_ * XP];       // 133,120 B
    __shared__ float red[8][LT][RP];    //  22,528 B
    __shared__ float a_s[LT][K_];       //   2,048 B

    const int n   = blockIdx.x;
    const int ch  = blockIdx.y;
    const int tid = threadIdx.x;
    const int l   = tid & 63;
    const int cg  = tid >> 6;

    const float* xbase = x + (size_t)n * C_ * L_ + ch * LT;

    // ---- issue ALL global loads up front (both halves in flight) ----
    float4 v0[8], v1[8];
#pragma unroll
    for (int j = 0; j < 8; ++j) {
        const int it = tid + j * 512;            // half 0: c in [0,256)
        const int c = it >> 4, q = it & 15;
        v0[j] = *reinterpret_cast<const float4*>(xbase + (size_t)c * L_ + q * 4);
    }
#pragma unroll
    for (int j = 0; j < 8; ++j) {
        const int it = tid + j * 512;            // half 1: c in [256,512)
        const int c = (it >> 4) + 256, q = it & 15;
        v1[j] = *reinterpret_cast<const float4*>(xbase + (size_t)c * L_ + q * 4);
    }

    // ---- write half 0 to LDS (waits only on v0's vmcnt), barrier ----
#pragma unroll
    for (int j = 0; j < 8; ++j) {
        const int it = tid + j * 512;
        const int c = it >> 4, q = it & 15;
        const int b = c * XP + q * 4;
        xs[b] = v0[j].x; xs[b + 1] = v0[j].y; xs[b + 2] = v0[j].z; xs[b + 3] = v0[j].w;
    }
    __syncthreads();

    // ---- phase A (half 0): wave cg owns c in [cg*32, +32); half1 still streaming
    const int c0 = __builtin_amdgcn_readfirstlane(cg) << 5;  // wave-uniform

    float acc[KG_];
#pragma unroll
    for (int k = 0; k < KG_; ++k) acc[k] = 0.f;

#pragma unroll
    for (int h = 0; h < 2; ++h) {
        const int cbase = c0 + h * 16;
        float xr[16];
#pragma unroll
        for (int ci = 0; ci < 16; ++ci)
            xr[ci] = xs[(cbase + ci) * XP + l];     // lanes->l: conflict-free
#pragma unroll
        for (int k = 0; k < KG_; ++k) {
            const float* w = cw + k * C_ + cbase;   // uniform addr -> s_load
#pragma unroll
            for (int ci = 0; ci < 16; ++ci)
                acc[k] = fmaf(w[ci], xr[ci], acc[k]);
        }
    }

    // ---- write half 1 to LDS (vmcnt dep on v1 only), barrier ----
#pragma unroll
    for (int j = 0; j < 8; ++j) {
        const int it = tid + j * 512;
        const int c = (it >> 4) + 256, q = it & 15;
        const int b = c * XP + q * 4;
        xs[b] = v1[j].x; xs[b + 1] = v1[j].y; xs[b + 2] = v1[j].z; xs[b + 3] = v1[j].w;
    }
    __syncthreads();

    // ---- phase A (half 1): wave cg owns c in [256 + cg*32, +32) ----
    const int c1 = 256 + c0;
#pragma unroll
    for (int h = 0; h < 2; ++h) {
        const int cbase = c1 + h * 16;
        float xr[16];
#pragma unroll
        for (int ci = 0; ci < 16; ++ci)
            xr[ci] = xs[(cbase + ci) * XP + l];
#pragma unroll
        for (int k = 0; k < KG_; ++k) {
            const float* w = cw + k * C_ + cbase;
#pragma unroll
            for (int ci = 0; ci < 16; ++ci)
                acc[k] = fmaf(w[ci], xr[ci], acc[k]);
        }
    }

#pragma unroll
    for (int k = 0; k < KG_; ++k) red[cg][l][k] = acc[k];
    __syncthreads();

    // reduce over the 8 c-groups
    for (int idx = tid; idx < LT * KG_; idx += 512) {
        const int li = idx / KG_, k = idx - li * KG_;
        float s = red[0][li][k];
#pragma unroll
        for (int g = 1; g < 8; ++g) s += red[g][li][k];
        red[0][li][k] = s;
    }
    __syncthreads();

    // ---- softmax over 10 k (wave 0, lane <-> l); a for k<8 into LDS ----
    if (tid < LT) {
        float v[KG_];
        float m = -1e30f;
#pragma unroll
        for (int k = 0; k < KG_; ++k) {
            v[k] = red[0][tid][k] + cb[k];
            m = fmaxf(m, v[k]);
        }
        float s = 0.f;
#pragma unroll
        for (int k = 0; k < KG_; ++k) { v[k] = __expf(v[k] - m); s += v[k]; }
        const float inv = 1.f / s;
#pragma unroll
        for (int k = 0; k < K_; ++k) {
            const float av = v[k] * inv;
            a_s[tid][k] = av;
            float t = av;                            // assign_sum over the 64 l
#pragma unroll
            for (int off = 32; off > 0; off >>= 1) t += __shfl_down(t, off);
            if (tid == 0)
                asum_part[((size_t)n * LCH + ch) * K_ + k] = t;
        }
    }
    __syncthreads();

    // ---- phase B: part[k][c] = sum_l a[k][l] * x[c][l]; thread <-> c ----
    const int c = tid;
    float bacc[K_];
#pragma unroll
    for (int k = 0; k < K_; ++k) bacc[k] = 0.f;

#pragma unroll 4
    for (int li = 0; li < LT; ++li) {
        const float xv = xs[c * XP + li];            // (c+li)%32: conflict-free
        const float4 a0 = *reinterpret_cast<const float4*>(&a_s[li][0]);  // broadcast
        const float4 a1 = *reinterpret_cast<const float4*>(&a_s[li][4]);  // broadcast
        bacc[0] = fmaf(a0.x, xv, bacc[0]);
        bacc[1] = fmaf(a0.y, xv, bacc[1]);
        bacc[2] = fmaf(a0.z, xv, bacc[2]);
        bacc[3] = fmaf(a0.w, xv, bacc[3]);
        bacc[4] = fmaf(a1.x, xv, bacc[4]);
        bacc[5] = fmaf(a1.y, xv, bacc[5]);
        bacc[6] = fmaf(a1.z, xv, bacc[6]);
        bacc[7] = fmaf(a1.w, xv, bacc[7]);
    }

    float* pp = part + (((size_t)n * LCH + ch) * K_) * C_ + c;
#pragma unroll
    for (int k = 0; k < K_; ++k)
        pp[(size_t)k * C_] = bacc[k];                // coalesced, no atomics
}

// ---------------------------------------------------------------------------
// k_final: reduce chunk partials, residual vs centers, per-k L2, global L2.
// grid N, block 512, thread <-> c.
// ---------------------------------------------------------------------------
__global__ __launch_bounds__(512) void k_final(
    const float* __restrict__ part, const float* __restrict__ asum_part,
    const float* __restrict__ centers, float* __restrict__ out)
{
    const int n    = blockIdx.x;
    const int tid  = threadIdx.x;
    const int lane = tid & 63;
    const int wv   = tid >> 6;

    __shared__ float s_asum[K_];
    __shared__ float s_inv[K_];
    __shared__ float s_q[K_];
    __shared__ float s_ginv;
    __shared__ float wred[8][K_];

    if (tid < K_) {
        float s = 0.f;
#pragma unroll
        for (int c2 = 0; c2 < LCH; ++c2)
            s += asum_part[((size_t)n * LCH + c2) * K_ + tid];
        s_asum[tid] = s;
    }
    __syncthreads();

    const int c = tid;
    float r[K_];
    float ssq[K_];
#pragma unroll
    for (int k = 0; k < K_; ++k) {
        float v = 0.f;
#pragma unroll
        for (int c2 = 0; c2 < LCH; ++c2)
            v += part[(((size_t)n * LCH + c2) * K_ + k) * C_ + c];
        v -= s_asum[k] * centers[k * C_ + c];
        r[k] = v;
        ssq[k] = v * v;
    }

#pragma unroll
    for (int k = 0; k < K_; ++k) {
        float t = ssq[k];
#pragma unroll
        for (int off = 32; off > 0; off >>= 1) t += __shfl_down(t, off);
        if (lane == 0) wred[wv][k] = t;
    }
    __syncthreads();

    if (tid < K_) {
        float t = 0.f;
#pragma unroll
        for (int w = 0; w < 8; ++w) t += wred[w][tid];
        const float inv = 1.f / fmaxf(sqrtf(t), EPSF);
        s_inv[tid] = inv;
        s_q[tid]   = t * inv * inv;
    }
    __syncthreads();

    if (tid == 0) {
        float g = 0.f;
#pragma unroll
        for (int k = 0; k < K_; ++k) g += s_q[k];
        s_ginv = 1.f / fmaxf(sqrtf(g), EPSF);
    }
    __syncthreads();

    const float ginv = s_ginv;
#pragma unroll
    for (int k = 0; k < K_; ++k)
        out[(size_t)n * (K_ * C_) + k * C_ + c] = r[k] * s_inv[k] * ginv;
}

// ---------------------------------------------------------------------------
extern "C" void kernel_launch(void* const* d_in, const int* in_sizes, int n_in,
                              void* d_out, int out_size, void* d_ws, size_t ws_size,
                              hipStream_t stream)
{
    const float* x       = (const float*)d_in[0];  // (32,512,16,32)
    const float* conv_w  = (const float*)d_in[1];  // (10,512)
    const float* conv_b  = (const float*)d_in[2];  // (10,)
    const float* centers = (const float*)d_in[3];  // (10,512)
    float* out = (float*)d_out;                    // (32, 4096)

    // ws layout (floats): part[N*LCH*K*C = 1,048,576] | asum_part[N*LCH*K = 2048]
    float* part      = (float*)d_ws;
    float* asum_part = part + (size_t)N_ * LCH * K_ * C_;

    dim3 grid(N_, LCH);
    hipLaunchKernelGGL(k_main, grid, dim3(512), 0, stream,
                       x, conv_w, conv_b, part, asum_part);
    hipLaunchKernelGGL(k_final, dim3(N_), dim3(512), 0, stream,
                       part, asum_part, centers, out);
}